// Round 11
// baseline (338.417 us; speedup 1.0000x reference)
//
#include <hip/hip_runtime.h>

#define N_NODES 100000
#define E_EDGES 1600000
#define F_IN    128
#define H_DIM   64
#define C_OUT   16
#define L_LAYERS 3
#define NTOT    (E_EDGES + N_NODES)
#define MAXD    64    // LDS-staged degree cap in agg (Poisson(16) max ~45); fallback recomputes

#define BKN2    512                                   // nodes per bucket
#define NB2     ((N_NODES + BKN2 - 1) / BKN2)         // 196
#define BCAP    9216                                  // per-bucket capacity
#define CH      8192                                  // edges per scatter block
#define PB      ((E_EDGES + CH - 1) / CH)             // 196

// bf16 helpers (RNE)
__device__ inline unsigned short f2bf(float f) {
    unsigned u = __float_as_uint(f);
    return (unsigned short)((u + 0x7FFFu + ((u >> 16) & 1u)) >> 16);
}
__device__ inline float bf_lo(unsigned p) { return __uint_as_float(p << 16); }
__device__ inline float bf_hi(unsigned p) { return __uint_as_float(p & 0xFFFF0000u); }

// ---------------- edge-index dtype detection ----------------
__global__ void detect64_kernel(const unsigned int* __restrict__ e, int* flag) {
    __shared__ int s_any;
    if (threadIdx.x == 0) s_any = 0;
    __syncthreads();
    int any = 0;
    for (int i = threadIdx.x; i < 2048; i += 256)
        if (e[2 * i + 1] != 0u) any = 1;
    if (any) atomicOr(&s_any, 1);
    __syncthreads();
    if (threadIdx.x == 0) *flag = s_any ? 0 : 1;
}

// ---------------- pass B: block-local bucket sort + dense scatter ----------------
__global__ __launch_bounds__(256) void bucket_scatter2(
        const void* __restrict__ eidx, const int* __restrict__ flag,
        int* __restrict__ bcur, unsigned int* __restrict__ packed) {
    __shared__ int cnt[NB2], basel[NB2], curl[NB2], gbase[NB2];
    __shared__ int sd[256];
    __shared__ unsigned int stage[CH];
    __shared__ unsigned char bkt[CH];
    int t = threadIdx.x;
    int b0 = blockIdx.x * CH;
    int ne = min(CH, E_EDGES - b0);
    for (int i = t; i < NB2; i += 256) cnt[i] = 0;
    __syncthreads();

    int f64 = *flag;
    int es[CH / 256], ed[CH / 256];
    #pragma unroll
    for (int j = 0; j < CH / 256; ++j) {
        int idx = b0 + j * 256 + t;
        if (idx < E_EDGES) {
            if (f64) {
                es[j] = (int)((const long long*)eidx)[idx];
                ed[j] = (int)((const long long*)eidx)[E_EDGES + idx];
            } else {
                es[j] = ((const int*)eidx)[idx];
                ed[j] = ((const int*)eidx)[E_EDGES + idx];
            }
            atomicAdd(&cnt[ed[j] >> 9], 1);
        } else { es[j] = -1; }
    }
    __syncthreads();
    int v = (t < NB2) ? cnt[t] : 0;
    sd[t] = v;
    __syncthreads();
    for (int off = 1; off < 256; off <<= 1) {
        int u = (t >= off) ? sd[t - off] : 0;
        __syncthreads();
        sd[t] += u;
        __syncthreads();
    }
    if (t < NB2) {
        basel[t] = sd[t] - v;
        curl[t] = 0;
        gbase[t] = atomicAdd(&bcur[t], v);
    }
    __syncthreads();
    #pragma unroll
    for (int j = 0; j < CH / 256; ++j) {
        if (es[j] >= 0) {
            int b = ed[j] >> 9;
            int r = atomicAdd(&curl[b], 1);
            int pos = basel[b] + r;
            stage[pos] = ((unsigned)(ed[j] & (BKN2 - 1)) << 17) | (unsigned)es[j];
            bkt[pos] = (unsigned char)b;
        }
    }
    __syncthreads();
    for (int i = t; i < ne; i += 256) {
        int b = bkt[i];
        packed[(size_t)b * BCAP + gbase[b] + (i - basel[b])] = stage[i];
    }
}

// ---------------- pass B2: exclusive scan of final bucket counts ----------------
__global__ __launch_bounds__(256) void bucket_scan2(
        const int* __restrict__ bcur, int* __restrict__ ebase) {
    __shared__ int sd[256];
    int t = threadIdx.x;
    int v = (t < NB2) ? bcur[t] : 0;
    sd[t] = v;
    __syncthreads();
    for (int off = 1; off < 256; off <<= 1) {
        int u = (t >= off) ? sd[t - off] : 0;
        __syncthreads();
        sd[t] += u;
        __syncthreads();
    }
    if (t < NB2) ebase[t] = sd[t] - v;
}

// ---------------- pass C: per-bucket CSR finalize ----------------
__global__ __launch_bounds__(256) void csr_build2(
        const unsigned int* __restrict__ packed, const int* __restrict__ bcur,
        const int* __restrict__ ebase,
        int* __restrict__ row_ptr, int* __restrict__ csr_src) {
    __shared__ int cnt[BKN2], scn[BKN2], cur[BKN2];
    int b = blockIdx.x, t = threadIdx.x;
    int nbase = b * BKN2;
    int nn = min(BKN2, N_NODES - nbase);
    int ec = bcur[b];
    size_t pbase = (size_t)b * BCAP;
    int cbase = ebase[b] + nbase;
    cnt[t] = (t < nn) ? 1 : 0;
    cnt[t + 256] = (t + 256 < nn) ? 1 : 0;
    __syncthreads();
    for (int i = t; i < ec; i += 256)
        atomicAdd(&cnt[packed[pbase + i] >> 17], 1);
    __syncthreads();
    scn[t] = cnt[t];
    scn[t + 256] = cnt[t + 256];
    __syncthreads();
    for (int off = 1; off < BKN2; off <<= 1) {
        int u0 = (t >= off) ? scn[t - off] : 0;
        int u1 = (t + 256 >= off) ? scn[t + 256 - off] : 0;
        __syncthreads();
        scn[t] += u0;
        scn[t + 256] += u1;
        __syncthreads();
    }
    #pragma unroll
    for (int q = 0; q < 2; ++q) {
        int idx = t + q * 256;
        if (idx < nn) {
            int offi = scn[idx] - cnt[idx];
            row_ptr[nbase + idx] = cbase + offi;
            csr_src[cbase + offi] = nbase + idx;   // self-loop first
            cur[idx] = offi + 1;
        }
    }
    if (b == NB2 - 1 && t == 0) row_ptr[N_NODES] = cbase + ec + nn;
    __syncthreads();
    for (int i = t; i < ec; i += 256) {
        unsigned p = packed[pbase + i];
        int dl = p >> 17, s = (int)(p & 0x1FFFFu);
        int pos = atomicAdd(&cur[dl], 1);
        csr_src[cbase + pos] = s;
    }
}

// ---------------- LDS-staged coalesced GEMM, balanced tile ----------------
// C[N x 64] = A[N x K] @ W[K x 64]; 64 rows/block, 4 rows x 4 cols/thread.
// A input fp32 (ABF16=0) or packed bf16 (ABF16=1, unpacked into fp32 LDS).
// Output C always packed bf16 (row = 32 uints). fp32 accumulation throughout.
// #pragma unroll 2 caps register pressure (R7 spill lesson).
#define GBR 64
#define KC  64
#define SAP (KC + 4)

template<int K, bool ACT, bool DOTS, bool ABF16>
__global__ __launch_bounds__(256) void gemm_lds_kernel(
        const void* __restrict__ Ain, const float* __restrict__ W,
        const float* __restrict__ bias,
        const float* __restrict__ asrc, const float* __restrict__ adst,
        unsigned* __restrict__ C, float* __restrict__ as_, float* __restrict__ ad_) {
    __shared__ __align__(16) float sW[KC * 64];      // 16 KB
    __shared__ __align__(16) float sA[GBR][SAP];     // 17.4 KB
    int t = threadIdx.x;
    int r0 = blockIdx.x * GBR;
    int wave = t >> 6, lane = t & 63;
    int tr = wave * 4 + (lane >> 4);     // 0..15; local rows tr + 16*i, i=0..3
    int c0 = (lane & 15) * 4;

    float acc[4][4];
    #pragma unroll
    for (int i = 0; i < 4; ++i)
        #pragma unroll
        for (int j = 0; j < 4; ++j) acc[i][j] = 0.f;

    for (int kc = 0; kc < K; kc += KC) {
        if (kc) __syncthreads();
        {
            const float4* W4 = (const float4*)(W + kc * 64);
            float4* sW4 = (float4*)sW;
            for (int i = t; i < KC * 16; i += 256) sW4[i] = W4[i];
        }
        if (ABF16) {
            const unsigned* A32 = (const unsigned*)Ain;
            for (int it = 0; it < (GBR * KC / 4) / 256; ++it) {
                int idx = it * 256 + t;
                int r = idx >> 4;        // / (KC/4)
                int c2 = idx & 15;       // uint2 within chunk row
                int gr = r0 + r;
                uint2 pv = make_uint2(0u, 0u);
                if (gr < N_NODES)
                    pv = *(const uint2*)&A32[(size_t)gr * (K / 2) + kc / 2 + c2 * 2];
                sA[r][c2 * 4 + 0] = bf_lo(pv.x);
                sA[r][c2 * 4 + 1] = bf_hi(pv.x);
                sA[r][c2 * 4 + 2] = bf_lo(pv.y);
                sA[r][c2 * 4 + 3] = bf_hi(pv.y);
            }
        } else {
            const float* A = (const float*)Ain;
            for (int it = 0; it < (GBR * KC / 4) / 256; ++it) {
                int idx = it * 256 + t;
                int r = idx >> 4;
                int c4 = idx & 15;
                int gr = r0 + r;
                float4 v = make_float4(0.f, 0.f, 0.f, 0.f);
                if (gr < N_NODES) v = *(const float4*)&A[(size_t)gr * K + kc + c4 * 4];
                *(float4*)&sA[r][c4 * 4] = v;
            }
        }
        __syncthreads();
        #pragma unroll 2
        for (int kk = 0; kk < KC; kk += 4) {
            float4 w0 = *(const float4*)&sW[(kk + 0) * 64 + c0];
            float4 w1 = *(const float4*)&sW[(kk + 1) * 64 + c0];
            float4 w2 = *(const float4*)&sW[(kk + 2) * 64 + c0];
            float4 w3 = *(const float4*)&sW[(kk + 3) * 64 + c0];
            #pragma unroll
            for (int i = 0; i < 4; ++i) {
                float4 a = *(const float4*)&sA[tr + 16 * i][kk];
                acc[i][0] += a.x * w0.x + a.y * w1.x + a.z * w2.x + a.w * w3.x;
                acc[i][1] += a.x * w0.y + a.y * w1.y + a.z * w2.y + a.w * w3.y;
                acc[i][2] += a.x * w0.z + a.y * w1.z + a.z * w2.z + a.w * w3.z;
                acc[i][3] += a.x * w0.w + a.y * w1.w + a.z * w2.w + a.w * w3.w;
            }
        }
    }

    float bs[4] = {0.f, 0.f, 0.f, 0.f};
    float av[4], dv[4];
    if (ACT) {
        #pragma unroll
        for (int j = 0; j < 4; ++j) bs[j] = bias[c0 + j];
    }
    if (DOTS) {
        #pragma unroll
        for (int j = 0; j < 4; ++j) { av[j] = asrc[c0 + j]; dv[j] = adst[c0 + j]; }
    }
    #pragma unroll
    for (int i = 0; i < 4; ++i) {
        int grow = r0 + tr + 16 * i;
        if (grow >= N_NODES) continue;
        float v0 = acc[i][0], v1 = acc[i][1], v2 = acc[i][2], v3 = acc[i][3];
        if (ACT) {
            v0 += bs[0]; v0 = v0 > 0.f ? v0 : 0.01f * v0;
            v1 += bs[1]; v1 = v1 > 0.f ? v1 : 0.01f * v1;
            v2 += bs[2]; v2 = v2 > 0.f ? v2 : 0.01f * v2;
            v3 += bs[3]; v3 = v3 > 0.f ? v3 : 0.01f * v3;
        }
        unsigned p0 = (unsigned)f2bf(v0) | ((unsigned)f2bf(v1) << 16);
        unsigned p1 = (unsigned)f2bf(v2) | ((unsigned)f2bf(v3) << 16);
        *(uint2*)&C[(size_t)grow * 32 + (c0 >> 1)] = make_uint2(p0, p1);
        if (DOTS) {
            float ds = acc[i][0] * av[0] + acc[i][1] * av[1] + acc[i][2] * av[2] + acc[i][3] * av[3];
            float dd = acc[i][0] * dv[0] + acc[i][1] * dv[1] + acc[i][2] * dv[2] + acc[i][3] * dv[3];
            #pragma unroll
            for (int off = 1; off < 16; off <<= 1) {
                ds += __shfl_xor(ds, off);
                dd += __shfl_xor(dd, off);
            }
            if ((lane & 15) == 0) { as_[grow] = ds; ad_[grow] = dd; }
        }
    }
}

// ---------------- fused aggregation (bf16 gather, 2 edges/wave, bf16 out) ----
__global__ __launch_bounds__(256) void agg_kernel(
        const int* __restrict__ row_ptr, const int* __restrict__ csr_src,
        const float* __restrict__ as_, const float* __restrict__ ad_,
        const unsigned* __restrict__ hw32, const float* __restrict__ bc,
        unsigned* __restrict__ hout32) {
    __shared__ float exbuf[4][MAXD];
    __shared__ int   sbuf[4][MAXD];
    int wave = threadIdx.x >> 6, lane = threadIdx.x & 63;
    int node = blockIdx.x * 4 + wave;
    if (node >= N_NODES) return;
    int rs = row_ptr[node], re = row_ptr[node + 1];
    int deg = re - rs;
    float aD = ad_[node];
    float psum = 0.f;
    for (int i = lane; i < deg; i += 64) {
        int s = csr_src[rs + i];
        float v = as_[s] + aD;
        v = v > 0.f ? v : 0.2f * v;
        float p = __expf(v);
        if (deg <= MAXD) { exbuf[wave][i] = p; sbuf[wave][i] = s; }
        psum += p;
    }
    #pragma unroll
    for (int off = 32; off >= 1; off >>= 1) psum += __shfl_xor(psum, off);
    float inv = 1.f / (psum + 1e-16f);

    int half = lane >> 5, fl = lane & 31;
    float acc0 = 0.f, acc1 = 0.f;
    if (deg <= MAXD) {
        int i = half;
        for (; i + 6 < deg; i += 8) {
            unsigned o0 = ((unsigned)sbuf[wave][i]     << 5) | fl;
            unsigned o1 = ((unsigned)sbuf[wave][i + 2] << 5) | fl;
            unsigned o2 = ((unsigned)sbuf[wave][i + 4] << 5) | fl;
            unsigned o3 = ((unsigned)sbuf[wave][i + 6] << 5) | fl;
            float w0 = exbuf[wave][i]     * inv, w1 = exbuf[wave][i + 2] * inv;
            float w2 = exbuf[wave][i + 4] * inv, w3 = exbuf[wave][i + 6] * inv;
            unsigned p0 = hw32[o0];
            unsigned p1 = hw32[o1];
            unsigned p2 = hw32[o2];
            unsigned p3 = hw32[o3];
            acc0 += w0 * bf_lo(p0) + w1 * bf_lo(p1) + w2 * bf_lo(p2) + w3 * bf_lo(p3);
            acc1 += w0 * bf_hi(p0) + w1 * bf_hi(p1) + w2 * bf_hi(p2) + w3 * bf_hi(p3);
        }
        for (; i < deg; i += 2) {
            float w = exbuf[wave][i] * inv;
            unsigned p = hw32[((unsigned)sbuf[wave][i] << 5) | fl];
            acc0 += w * bf_lo(p);
            acc1 += w * bf_hi(p);
        }
    } else {
        for (int i = half; i < deg; i += 2) {
            int s = csr_src[rs + i];
            float v = as_[s] + aD;
            v = v > 0.f ? v : 0.2f * v;
            float w = __expf(v) * inv;
            unsigned p = hw32[((unsigned)s << 5) | fl];
            acc0 += w * bf_lo(p);
            acc1 += w * bf_hi(p);
        }
    }
    acc0 += __shfl_xor(acc0, 32);
    acc1 += __shfl_xor(acc1, 32);
    if (half == 0) {
        float v0 = acc0 + bc[2 * fl];
        float v1 = acc1 + bc[2 * fl + 1];
        v0 = v0 > 0.f ? v0 : 0.01f * v0;
        v1 = v1 > 0.f ? v1 : 0.01f * v1;
        hout32[((unsigned)node << 5) | fl] = (unsigned)f2bf(v0) | ((unsigned)f2bf(v1) << 16);
    }
}

// ---------------- output GEMM + log_softmax (bf16 h input) ----------------
__global__ __launch_bounds__(256) void out_logsoftmax_kernel(
        const unsigned* __restrict__ h32, const float* __restrict__ W,
        const float* __restrict__ b, float* __restrict__ out) {
    __shared__ float sW[H_DIM * C_OUT];
    __shared__ float sh[16][H_DIM];
    __shared__ float sb[C_OUT];
    int t = threadIdx.x;
    for (int i = t; i < H_DIM * C_OUT; i += 256) sW[i] = W[i];
    if (t < C_OUT) sb[t] = b[t];
    int row0 = blockIdx.x * 16;
    #pragma unroll
    for (int it = 0; it < 2; ++it) {
        int idx = it * 256 + t;          // 0..511 ; 16 rows x 32 uints
        int r = idx >> 5, c2 = idx & 31;
        unsigned u = h32[((unsigned)(row0 + r) << 5) | c2];
        sh[r][c2 * 2] = bf_lo(u);
        sh[r][c2 * 2 + 1] = bf_hi(u);
    }
    __syncthreads();
    int r = t >> 4, c = t & 15;
    float acc = sb[c];
    #pragma unroll
    for (int k = 0; k < H_DIM; ++k) acc += sh[r][k] * sW[k * C_OUT + c];
    float m = acc;
    #pragma unroll
    for (int off = 8; off >= 1; off >>= 1) m = fmaxf(m, __shfl_xor(m, off, 16));
    float e = __expf(acc - m);
    float ssum = e;
    #pragma unroll
    for (int off = 8; off >= 1; off >>= 1) ssum += __shfl_xor(ssum, off, 16);
    out[(row0 + r) * C_OUT + c] = acc - m - __logf(ssum);
}

extern "C" void kernel_launch(void* const* d_in, const int* in_sizes, int n_in,
                              void* d_out, int out_size, void* d_ws, size_t ws_size,
                              hipStream_t stream) {
    const float* x     = (const float*)d_in[0];
    const void*  eidx  = d_in[1];
    const float* W_in  = (const float*)d_in[3];
    const float* b_in  = (const float*)d_in[4];
    const float* Wc    = (const float*)d_in[5];
    const float* a_src = (const float*)d_in[6];
    const float* a_dst = (const float*)d_in[7];
    const float* bc    = (const float*)d_in[8];
    const float* W_out = (const float*)d_in[9];
    const float* b_out = (const float*)d_in[10];
    float* out = (float*)d_out;

    // workspace layout: h, hw are packed-bf16 node-feature tables (N x 32 uints)
    unsigned* h     = (unsigned*)d_ws;                     // N*32 uints
    unsigned* hw    = h + (size_t)N_NODES * 32;            // N*32 uints
    float* as_      = (float*)(hw + (size_t)N_NODES * 32); // N
    float* ad_      = as_ + N_NODES;                       // N
    int*   row_ptr  = (int*)(ad_ + N_NODES);               // N+1
    int*   csr_src  = row_ptr + N_NODES + 1;               // E+N
    unsigned int* packed = (unsigned int*)(csr_src + NTOT);// NB2*BCAP
    int*   bcur     = (int*)(packed + (size_t)NB2 * BCAP); // NB2
    int*   ebase    = bcur + NB2;                          // NB2
    int*   flag     = ebase + NB2;                         // 1

    detect64_kernel<<<1, 256, 0, stream>>>((const unsigned int*)eidx, flag);
    hipMemsetAsync(bcur, 0, NB2 * sizeof(int), stream);
    bucket_scatter2<<<PB, 256, 0, stream>>>(eidx, flag, bcur, packed);
    bucket_scan2<<<1, 256, 0, stream>>>(bcur, ebase);
    csr_build2<<<NB2, 256, 0, stream>>>(packed, bcur, ebase, row_ptr, csr_src);

    int gblocks = (N_NODES + GBR - 1) / GBR;
    gemm_lds_kernel<F_IN, true, false, false><<<gblocks, 256, 0, stream>>>(
        x, W_in, b_in, nullptr, nullptr, h, nullptr, nullptr);

    unsigned* hin = h;
    unsigned* hx  = hw;
    for (int l = 0; l < L_LAYERS; ++l) {
        gemm_lds_kernel<H_DIM, false, true, true><<<gblocks, 256, 0, stream>>>(
            hin, Wc + l * H_DIM * H_DIM, nullptr,
            a_src + l * H_DIM, a_dst + l * H_DIM, hx, as_, ad_);
        agg_kernel<<<(N_NODES + 3) / 4, 256, 0, stream>>>(
            row_ptr, csr_src, as_, ad_, hx, bc + l * H_DIM, hin);
    }

    out_logsoftmax_kernel<<<N_NODES / 16, 256, 0, stream>>>(hin, W_out, b_out, out);
}

// Round 12
// 303.823 us; speedup vs baseline: 1.1139x; 1.1139x over previous
//
#include <hip/hip_runtime.h>

#define N_NODES 100000
#define E_EDGES 1600000
#define F_IN    128
#define H_DIM   64
#define C_OUT   16
#define L_LAYERS 3
#define NTOT    (E_EDGES + N_NODES)
#define MAXD    64    // LDS-staged degree cap in agg; fallback recomputes

#define BKN2    512
#define NB2     ((N_NODES + BKN2 - 1) / BKN2)         // 196
#define BCAP    9216
#define CH      8192
#define PB      ((E_EDGES + CH - 1) / CH)             // 196

typedef __attribute__((ext_vector_type(8))) short short8;
typedef __attribute__((ext_vector_type(4))) float f32x4;

// bf16 helpers
__device__ inline unsigned short f2bf(float f) {
    unsigned u = __float_as_uint(f);
    return (unsigned short)((u + 0x7FFFu + ((u >> 16) & 1u)) >> 16);
}
__device__ inline float bf_lo(unsigned p) { return __uint_as_float(p << 16); }
__device__ inline float bf_hi(unsigned p) { return __uint_as_float(p & 0xFFFF0000u); }
__device__ inline unsigned cvt_pk_bf16(float lo, float hi) {
    unsigned r;
    asm("v_cvt_pk_bf16_f32 %0, %1, %2" : "=v"(r) : "v"(lo), "v"(hi));
    return r;
}

// ---------------- edge-index dtype detection ----------------
__global__ void detect64_kernel(const unsigned int* __restrict__ e, int* flag) {
    __shared__ int s_any;
    if (threadIdx.x == 0) s_any = 0;
    __syncthreads();
    int any = 0;
    for (int i = threadIdx.x; i < 2048; i += 256)
        if (e[2 * i + 1] != 0u) any = 1;
    if (any) atomicOr(&s_any, 1);
    __syncthreads();
    if (threadIdx.x == 0) *flag = s_any ? 0 : 1;
}

// ---------------- pass B: block-local bucket sort + dense scatter ----------------
__global__ __launch_bounds__(256) void bucket_scatter2(
        const void* __restrict__ eidx, const int* __restrict__ flag,
        int* __restrict__ bcur, unsigned int* __restrict__ packed) {
    __shared__ int cnt[NB2], basel[NB2], curl[NB2], gbase[NB2];
    __shared__ int sd[256];
    __shared__ unsigned int stage[CH];
    __shared__ unsigned char bkt[CH];
    int t = threadIdx.x;
    int b0 = blockIdx.x * CH;
    int ne = min(CH, E_EDGES - b0);
    for (int i = t; i < NB2; i += 256) cnt[i] = 0;
    __syncthreads();

    int f64 = *flag;
    int es[CH / 256], ed[CH / 256];
    #pragma unroll
    for (int j = 0; j < CH / 256; ++j) {
        int idx = b0 + j * 256 + t;
        if (idx < E_EDGES) {
            if (f64) {
                es[j] = (int)((const long long*)eidx)[idx];
                ed[j] = (int)((const long long*)eidx)[E_EDGES + idx];
            } else {
                es[j] = ((const int*)eidx)[idx];
                ed[j] = ((const int*)eidx)[E_EDGES + idx];
            }
            atomicAdd(&cnt[ed[j] >> 9], 1);
        } else { es[j] = -1; }
    }
    __syncthreads();
    int v = (t < NB2) ? cnt[t] : 0;
    sd[t] = v;
    __syncthreads();
    for (int off = 1; off < 256; off <<= 1) {
        int u = (t >= off) ? sd[t - off] : 0;
        __syncthreads();
        sd[t] += u;
        __syncthreads();
    }
    if (t < NB2) {
        basel[t] = sd[t] - v;
        curl[t] = 0;
        gbase[t] = atomicAdd(&bcur[t], v);
    }
    __syncthreads();
    #pragma unroll
    for (int j = 0; j < CH / 256; ++j) {
        if (es[j] >= 0) {
            int b = ed[j] >> 9;
            int r = atomicAdd(&curl[b], 1);
            int pos = basel[b] + r;
            stage[pos] = ((unsigned)(ed[j] & (BKN2 - 1)) << 17) | (unsigned)es[j];
            bkt[pos] = (unsigned char)b;
        }
    }
    __syncthreads();
    for (int i = t; i < ne; i += 256) {
        int b = bkt[i];
        packed[(size_t)b * BCAP + gbase[b] + (i - basel[b])] = stage[i];
    }
}

// ---------------- pass B2: exclusive scan of final bucket counts ----------------
__global__ __launch_bounds__(256) void bucket_scan2(
        const int* __restrict__ bcur, int* __restrict__ ebase) {
    __shared__ int sd[256];
    int t = threadIdx.x;
    int v = (t < NB2) ? bcur[t] : 0;
    sd[t] = v;
    __syncthreads();
    for (int off = 1; off < 256; off <<= 1) {
        int u = (t >= off) ? sd[t - off] : 0;
        __syncthreads();
        sd[t] += u;
        __syncthreads();
    }
    if (t < NB2) ebase[t] = sd[t] - v;
}

// ---------------- pass C: per-bucket CSR finalize ----------------
__global__ __launch_bounds__(256) void csr_build2(
        const unsigned int* __restrict__ packed, const int* __restrict__ bcur,
        const int* __restrict__ ebase,
        int* __restrict__ row_ptr, int* __restrict__ csr_src) {
    __shared__ int cnt[BKN2], scn[BKN2], cur[BKN2];
    int b = blockIdx.x, t = threadIdx.x;
    int nbase = b * BKN2;
    int nn = min(BKN2, N_NODES - nbase);
    int ec = bcur[b];
    size_t pbase = (size_t)b * BCAP;
    int cbase = ebase[b] + nbase;
    cnt[t] = (t < nn) ? 1 : 0;
    cnt[t + 256] = (t + 256 < nn) ? 1 : 0;
    __syncthreads();
    for (int i = t; i < ec; i += 256)
        atomicAdd(&cnt[packed[pbase + i] >> 17], 1);
    __syncthreads();
    scn[t] = cnt[t];
    scn[t + 256] = cnt[t + 256];
    __syncthreads();
    for (int off = 1; off < BKN2; off <<= 1) {
        int u0 = (t >= off) ? scn[t - off] : 0;
        int u1 = (t + 256 >= off) ? scn[t + 256 - off] : 0;
        __syncthreads();
        scn[t] += u0;
        scn[t + 256] += u1;
        __syncthreads();
    }
    #pragma unroll
    for (int q = 0; q < 2; ++q) {
        int idx = t + q * 256;
        if (idx < nn) {
            int offi = scn[idx] - cnt[idx];
            row_ptr[nbase + idx] = cbase + offi;
            csr_src[cbase + offi] = nbase + idx;   // self-loop first
            cur[idx] = offi + 1;
        }
    }
    if (b == NB2 - 1 && t == 0) row_ptr[N_NODES] = cbase + ec + nn;
    __syncthreads();
    for (int i = t; i < ec; i += 256) {
        unsigned p = packed[pbase + i];
        int dl = p >> 17, s = (int)(p & 0x1FFFFu);
        int pos = atomicAdd(&cur[dl], 1);
        csr_src[cbase + pos] = s;
    }
}

// ---------------- input GEMM (fp32 LDS-staged, R8 structure) ----------------
#define GBR 64
#define KC  64
#define SAP (KC + 4)

__global__ __launch_bounds__(256) void gemm_in_kernel(
        const float* __restrict__ A, const float* __restrict__ W,
        const float* __restrict__ bias, unsigned* __restrict__ C) {
    __shared__ __align__(16) float sW[KC * 64];
    __shared__ __align__(16) float sA[GBR][SAP];
    int t = threadIdx.x;
    int r0 = blockIdx.x * GBR;
    int wave = t >> 6, lane = t & 63;
    int tr = wave * 4 + (lane >> 4);
    int c0 = (lane & 15) * 4;

    float acc[4][4];
    #pragma unroll
    for (int i = 0; i < 4; ++i)
        #pragma unroll
        for (int j = 0; j < 4; ++j) acc[i][j] = 0.f;

    for (int kc = 0; kc < F_IN; kc += KC) {
        if (kc) __syncthreads();
        {
            const float4* W4 = (const float4*)(W + kc * 64);
            float4* sW4 = (float4*)sW;
            for (int i = t; i < KC * 16; i += 256) sW4[i] = W4[i];
        }
        for (int it = 0; it < (GBR * KC / 4) / 256; ++it) {
            int idx = it * 256 + t;
            int r = idx >> 4;
            int c4 = idx & 15;
            int gr = r0 + r;
            float4 v = make_float4(0.f, 0.f, 0.f, 0.f);
            if (gr < N_NODES) v = *(const float4*)&A[(size_t)gr * F_IN + kc + c4 * 4];
            *(float4*)&sA[r][c4 * 4] = v;
        }
        __syncthreads();
        #pragma unroll 2
        for (int kk = 0; kk < KC; kk += 4) {
            float4 w0 = *(const float4*)&sW[(kk + 0) * 64 + c0];
            float4 w1 = *(const float4*)&sW[(kk + 1) * 64 + c0];
            float4 w2 = *(const float4*)&sW[(kk + 2) * 64 + c0];
            float4 w3 = *(const float4*)&sW[(kk + 3) * 64 + c0];
            #pragma unroll
            for (int i = 0; i < 4; ++i) {
                float4 a = *(const float4*)&sA[tr + 16 * i][kk];
                acc[i][0] += a.x * w0.x + a.y * w1.x + a.z * w2.x + a.w * w3.x;
                acc[i][1] += a.x * w0.y + a.y * w1.y + a.z * w2.y + a.w * w3.y;
                acc[i][2] += a.x * w0.z + a.y * w1.z + a.z * w2.z + a.w * w3.z;
                acc[i][3] += a.x * w0.w + a.y * w1.w + a.z * w2.w + a.w * w3.w;
            }
        }
    }

    float bs[4];
    #pragma unroll
    for (int j = 0; j < 4; ++j) bs[j] = bias[c0 + j];
    #pragma unroll
    for (int i = 0; i < 4; ++i) {
        int grow = r0 + tr + 16 * i;
        if (grow >= N_NODES) continue;
        float v0 = acc[i][0] + bs[0]; v0 = v0 > 0.f ? v0 : 0.01f * v0;
        float v1 = acc[i][1] + bs[1]; v1 = v1 > 0.f ? v1 : 0.01f * v1;
        float v2 = acc[i][2] + bs[2]; v2 = v2 > 0.f ? v2 : 0.01f * v2;
        float v3 = acc[i][3] + bs[3]; v3 = v3 > 0.f ? v3 : 0.01f * v3;
        *(uint2*)&C[(size_t)grow * 32 + (c0 >> 1)] =
            make_uint2(cvt_pk_bf16(v0, v1), cvt_pk_bf16(v2, v3));
    }
}

// ---------------- MFMA layer GEMM: C[N x 64] = A_bf16[N x 64] @ W[64 x 64] ---
// 64 rows/block (4 waves x 16 rows). W -> transposed bf16 LDS [j][k] (pad 72).
// Per wave: 8x mfma_f32_16x16x32_bf16. DOTS epilogue from fp32 accs; C packed
// bf16 via LDS transpose + v_cvt_pk_bf16_f32.
// Frag layout (guide §3): A row=l&15, k=(l>>4)*8+j ; B col=l&15, same k ;
// C/D col=lane&15, row=(lane>>4)*4+reg (m89-verified).
__global__ __launch_bounds__(256) void gemm_mfma_kernel(
        const unsigned* __restrict__ A32, const float* __restrict__ W,
        const float* __restrict__ asrc, const float* __restrict__ adst,
        unsigned* __restrict__ C, float* __restrict__ as_, float* __restrict__ ad_) {
    __shared__ __align__(16) unsigned short sWT[64][72];  // 9 KB
    __shared__ float sAv[64], sDv[64];
    __shared__ __align__(16) float sTile[4][16 * 64];     // 16 KB
    int t = threadIdx.x;
    // stage W transposed as bf16
    for (int i = t; i < 64 * 64; i += 256) {
        int k = i >> 6, j = i & 63;
        sWT[j][k] = f2bf(W[i]);
    }
    if (t < 64) { sAv[t] = asrc[t]; sDv[t] = adst[t]; }
    __syncthreads();

    int wave = t >> 6, lane = t & 63;
    int r0 = blockIdx.x * 64 + wave * 16;
    int cj = lane & 15, kq = lane >> 4;

    int ra = r0 + cj;                      // A row this lane loads
    if (ra >= N_NODES) ra = N_NODES - 1;   // clamp; masked on store
    const short8* arow = (const short8*)&A32[(size_t)ra * 32];
    short8 a0 = arow[kq];        // k 0..31
    short8 a1 = arow[4 + kq];    // k 32..63

    f32x4 zero = {0.f, 0.f, 0.f, 0.f};
    f32x4 acc[4] = {zero, zero, zero, zero};
    #pragma unroll
    for (int ct = 0; ct < 4; ++ct) {
        short8 b0 = *(const short8*)&sWT[16 * ct + cj][kq * 8];
        short8 b1 = *(const short8*)&sWT[16 * ct + cj][32 + kq * 8];
        acc[ct] = __builtin_amdgcn_mfma_f32_16x16x32_bf16(a0, b0, acc[ct], 0, 0, 0);
        acc[ct] = __builtin_amdgcn_mfma_f32_16x16x32_bf16(a1, b1, acc[ct], 0, 0, 0);
    }

    // DOTS epilogue: row = (lane>>4)*4 + r, col = ct*16 + cj
    float av[4], dv[4];
    #pragma unroll
    for (int ct = 0; ct < 4; ++ct) { av[ct] = sAv[ct * 16 + cj]; dv[ct] = sDv[ct * 16 + cj]; }
    #pragma unroll
    for (int r = 0; r < 4; ++r) {
        float ds = acc[0][r] * av[0] + acc[1][r] * av[1] + acc[2][r] * av[2] + acc[3][r] * av[3];
        float dd = acc[0][r] * dv[0] + acc[1][r] * dv[1] + acc[2][r] * dv[2] + acc[3][r] * dv[3];
        #pragma unroll
        for (int off = 1; off < 16; off <<= 1) {
            ds += __shfl_xor(ds, off);
            dd += __shfl_xor(dd, off);
        }
        int grow = r0 + kq * 4 + r;
        if (cj == 0 && grow < N_NODES) { as_[grow] = ds; ad_[grow] = dd; }
    }

    // C write: transpose via LDS, pack bf16
    float* tl = sTile[wave];
    #pragma unroll
    for (int ct = 0; ct < 4; ++ct)
        #pragma unroll
        for (int r = 0; r < 4; ++r)
            tl[(kq * 4 + r) * 64 + ct * 16 + cj] = acc[ct][r];
    // same-wave RAW: compiler inserts lgkmcnt wait
    unsigned ur[8];
    #pragma unroll
    for (int i = 0; i < 8; ++i) {
        float2 fp = *(const float2*)&tl[(lane * 8 + i) * 2];
        ur[i] = cvt_pk_bf16(fp.x, fp.y);
    }
    int grow = r0 + (lane >> 2);
    if (grow < N_NODES) {
        uint4* dst = (uint4*)&C[(size_t)grow * 32 + (lane & 3) * 8];
        dst[0] = make_uint4(ur[0], ur[1], ur[2], ur[3]);
        dst[1] = make_uint4(ur[4], ur[5], ur[6], ur[7]);
    }
}

// ---------------- fused aggregation (bf16 gather, 2 edges/wave, bf16 out) ----
// Unnormalized accumulate (inv folded into epilogue).
__global__ __launch_bounds__(256) void agg_kernel(
        const int* __restrict__ row_ptr, const int* __restrict__ csr_src,
        const float* __restrict__ as_, const float* __restrict__ ad_,
        const unsigned* __restrict__ hw32, const float* __restrict__ bc,
        unsigned* __restrict__ hout32) {
    __shared__ float exbuf[4][MAXD];
    __shared__ int   sbuf[4][MAXD];
    int wave = threadIdx.x >> 6, lane = threadIdx.x & 63;
    int node = blockIdx.x * 4 + wave;
    if (node >= N_NODES) return;
    int rs = row_ptr[node], re = row_ptr[node + 1];
    int deg = re - rs;
    float aD = ad_[node];
    float psum = 0.f;
    for (int i = lane; i < deg; i += 64) {
        int s = csr_src[rs + i];
        float v = as_[s] + aD;
        v = v > 0.f ? v : 0.2f * v;
        float p = __expf(v);
        if (deg <= MAXD) { exbuf[wave][i] = p; sbuf[wave][i] = s; }
        psum += p;
    }
    #pragma unroll
    for (int off = 32; off >= 1; off >>= 1) psum += __shfl_xor(psum, off);
    float inv = 1.f / (psum + 1e-16f);

    int half = lane >> 5, fl = lane & 31;
    float acc0 = 0.f, acc1 = 0.f;
    if (deg <= MAXD) {
        int i = half;
        for (; i + 6 < deg; i += 8) {
            unsigned o0 = ((unsigned)sbuf[wave][i]     << 5) | fl;
            unsigned o1 = ((unsigned)sbuf[wave][i + 2] << 5) | fl;
            unsigned o2 = ((unsigned)sbuf[wave][i + 4] << 5) | fl;
            unsigned o3 = ((unsigned)sbuf[wave][i + 6] << 5) | fl;
            float w0 = exbuf[wave][i],     w1 = exbuf[wave][i + 2];
            float w2 = exbuf[wave][i + 4], w3 = exbuf[wave][i + 6];
            unsigned p0 = hw32[o0];
            unsigned p1 = hw32[o1];
            unsigned p2 = hw32[o2];
            unsigned p3 = hw32[o3];
            acc0 += w0 * bf_lo(p0) + w1 * bf_lo(p1) + w2 * bf_lo(p2) + w3 * bf_lo(p3);
            acc1 += w0 * bf_hi(p0) + w1 * bf_hi(p1) + w2 * bf_hi(p2) + w3 * bf_hi(p3);
        }
        for (; i < deg; i += 2) {
            float w = exbuf[wave][i];
            unsigned p = hw32[((unsigned)sbuf[wave][i] << 5) | fl];
            acc0 += w * bf_lo(p);
            acc1 += w * bf_hi(p);
        }
    } else {
        for (int i = half; i < deg; i += 2) {
            int s = csr_src[rs + i];
            float v = as_[s] + aD;
            v = v > 0.f ? v : 0.2f * v;
            float w = __expf(v);
            unsigned p = hw32[((unsigned)s << 5) | fl];
            acc0 += w * bf_lo(p);
            acc1 += w * bf_hi(p);
        }
    }
    acc0 += __shfl_xor(acc0, 32);
    acc1 += __shfl_xor(acc1, 32);
    if (half == 0) {
        float v0 = acc0 * inv + bc[2 * fl];
        float v1 = acc1 * inv + bc[2 * fl + 1];
        v0 = v0 > 0.f ? v0 : 0.01f * v0;
        v1 = v1 > 0.f ? v1 : 0.01f * v1;
        hout32[((unsigned)node << 5) | fl] = cvt_pk_bf16(v0, v1);
    }
}

// ---------------- output GEMM + log_softmax (bf16 h input) ----------------
__global__ __launch_bounds__(256) void out_logsoftmax_kernel(
        const unsigned* __restrict__ h32, const float* __restrict__ W,
        const float* __restrict__ b, float* __restrict__ out) {
    __shared__ float sW[H_DIM * C_OUT];
    __shared__ float sh[16][H_DIM];
    __shared__ float sb[C_OUT];
    int t = threadIdx.x;
    for (int i = t; i < H_DIM * C_OUT; i += 256) sW[i] = W[i];
    if (t < C_OUT) sb[t] = b[t];
    int row0 = blockIdx.x * 16;
    #pragma unroll
    for (int it = 0; it < 2; ++it) {
        int idx = it * 256 + t;
        int r = idx >> 5, c2 = idx & 31;
        unsigned u = h32[((unsigned)(row0 + r) << 5) | c2];
        sh[r][c2 * 2] = bf_lo(u);
        sh[r][c2 * 2 + 1] = bf_hi(u);
    }
    __syncthreads();
    int r = t >> 4, c = t & 15;
    float acc = sb[c];
    #pragma unroll
    for (int k = 0; k < H_DIM; ++k) acc += sh[r][k] * sW[k * C_OUT + c];
    float m = acc;
    #pragma unroll
    for (int off = 8; off >= 1; off >>= 1) m = fmaxf(m, __shfl_xor(m, off, 16));
    float e = __expf(acc - m);
    float ssum = e;
    #pragma unroll
    for (int off = 8; off >= 1; off >>= 1) ssum += __shfl_xor(ssum, off, 16);
    out[(row0 + r) * C_OUT + c] = acc - m - __logf(ssum);
}

extern "C" void kernel_launch(void* const* d_in, const int* in_sizes, int n_in,
                              void* d_out, int out_size, void* d_ws, size_t ws_size,
                              hipStream_t stream) {
    const float* x     = (const float*)d_in[0];
    const void*  eidx  = d_in[1];
    const float* W_in  = (const float*)d_in[3];
    const float* b_in  = (const float*)d_in[4];
    const float* Wc    = (const float*)d_in[5];
    const float* a_src = (const float*)d_in[6];
    const float* a_dst = (const float*)d_in[7];
    const float* bc    = (const float*)d_in[8];
    const float* W_out = (const float*)d_in[9];
    const float* b_out = (const float*)d_in[10];
    float* out = (float*)d_out;

    // workspace layout: h, hw are packed-bf16 node-feature tables (N x 32 uints)
    unsigned* h     = (unsigned*)d_ws;                     // N*32 uints
    unsigned* hw    = h + (size_t)N_NODES * 32;            // N*32 uints
    float* as_      = (float*)(hw + (size_t)N_NODES * 32); // N
    float* ad_      = as_ + N_NODES;                       // N
    int*   row_ptr  = (int*)(ad_ + N_NODES);               // N+1
    int*   csr_src  = row_ptr + N_NODES + 1;               // E+N
    unsigned int* packed = (unsigned int*)(csr_src + NTOT);// NB2*BCAP
    int*   bcur     = (int*)(packed + (size_t)NB2 * BCAP); // NB2
    int*   ebase    = bcur + NB2;                          // NB2
    int*   flag     = ebase + NB2;                         // 1

    detect64_kernel<<<1, 256, 0, stream>>>((const unsigned int*)eidx, flag);
    hipMemsetAsync(bcur, 0, NB2 * sizeof(int), stream);
    bucket_scatter2<<<PB, 256, 0, stream>>>(eidx, flag, bcur, packed);
    bucket_scan2<<<1, 256, 0, stream>>>(bcur, ebase);
    csr_build2<<<NB2, 256, 0, stream>>>(packed, bcur, ebase, row_ptr, csr_src);

    gemm_in_kernel<<<(N_NODES + GBR - 1) / GBR, 256, 0, stream>>>(x, W_in, b_in, h);

    unsigned* hin = h;
    unsigned* hx  = hw;
    int mblocks = (N_NODES + 63) / 64;
    for (int l = 0; l < L_LAYERS; ++l) {
        gemm_mfma_kernel<<<mblocks, 256, 0, stream>>>(
            hin, Wc + l * H_DIM * H_DIM,
            a_src + l * H_DIM, a_dst + l * H_DIM, hx, as_, ad_);
        agg_kernel<<<(N_NODES + 3) / 4, 256, 0, stream>>>(
            row_ptr, csr_src, as_, ad_, hx, bc + l * H_DIM, hin);
    }

    out_logsoftmax_kernel<<<N_NODES / 16, 256, 0, stream>>>(hin, W_out, b_out, out);
}

// Round 13
// 297.459 us; speedup vs baseline: 1.1377x; 1.0214x over previous
//
#include <hip/hip_runtime.h>

#define N_NODES 100000
#define E_EDGES 1600000
#define F_IN    128
#define H_DIM   64
#define C_OUT   16
#define L_LAYERS 3
#define NTOT    (E_EDGES + N_NODES)
#define MAXD    64    // LDS-staged degree cap in agg; fallback recomputes

#define BKN2    512
#define NB2     ((N_NODES + BKN2 - 1) / BKN2)         // 196
#define BCAP    9216
#define CH      8192
#define PB      ((E_EDGES + CH - 1) / CH)             // 196

typedef __attribute__((ext_vector_type(8))) short short8;
typedef __attribute__((ext_vector_type(4))) float f32x4;

// bf16 helpers
__device__ inline unsigned short f2bf(float f) {
    unsigned u = __float_as_uint(f);
    return (unsigned short)((u + 0x7FFFu + ((u >> 16) & 1u)) >> 16);
}
__device__ inline float bf_lo(unsigned p) { return __uint_as_float(p << 16); }
__device__ inline float bf_hi(unsigned p) { return __uint_as_float(p & 0xFFFF0000u); }
__device__ inline unsigned cvt_pk_bf16(float lo, float hi) {
    unsigned r;
    asm("v_cvt_pk_bf16_f32 %0, %1, %2" : "=v"(r) : "v"(lo), "v"(hi));
    return r;
}

// ---------------- pass B: block-local bucket sort + dense scatter ----------------
// Edge dtype (int32 vs int64) detected per-block by sampling odd dwords of the
// block's own chunk (int64 -> all high-words zero; int32 -> random src values).
__global__ __launch_bounds__(256) void bucket_scatter2(
        const void* __restrict__ eidx,
        int* __restrict__ bcur, unsigned int* __restrict__ packed) {
    __shared__ int cnt[NB2], basel[NB2], curl[NB2], gbase[NB2];
    __shared__ int sd[256];
    __shared__ int sflag;
    __shared__ unsigned int stage[CH];
    __shared__ unsigned char bkt[CH];
    int t = threadIdx.x;
    int b0 = blockIdx.x * CH;
    int ne = min(CH, E_EDGES - b0);
    if (t == 0) sflag = 0;
    for (int i = t; i < NB2; i += 256) cnt[i] = 0;
    __syncthreads();
    // dtype detection on this chunk
    {
        int nsamp = min(ne, 1024);
        int any = 0;
        for (int j = t; j < nsamp; j += 256)
            if (((const unsigned*)eidx)[2 * (size_t)(b0 + j) + 1] != 0u) any = 1;
        if (any) atomicOr(&sflag, 1);
    }
    __syncthreads();
    int f64 = sflag ? 0 : 1;

    int es[CH / 256], ed[CH / 256];
    #pragma unroll
    for (int j = 0; j < CH / 256; ++j) {
        int idx = b0 + j * 256 + t;
        if (idx < E_EDGES) {
            if (f64) {
                es[j] = (int)((const long long*)eidx)[idx];
                ed[j] = (int)((const long long*)eidx)[E_EDGES + idx];
            } else {
                es[j] = ((const int*)eidx)[idx];
                ed[j] = ((const int*)eidx)[E_EDGES + idx];
            }
            atomicAdd(&cnt[ed[j] >> 9], 1);
        } else { es[j] = -1; }
    }
    __syncthreads();
    int v = (t < NB2) ? cnt[t] : 0;
    sd[t] = v;
    __syncthreads();
    for (int off = 1; off < 256; off <<= 1) {
        int u = (t >= off) ? sd[t - off] : 0;
        __syncthreads();
        sd[t] += u;
        __syncthreads();
    }
    if (t < NB2) {
        basel[t] = sd[t] - v;
        curl[t] = 0;
        gbase[t] = atomicAdd(&bcur[t], v);
    }
    __syncthreads();
    #pragma unroll
    for (int j = 0; j < CH / 256; ++j) {
        if (es[j] >= 0) {
            int b = ed[j] >> 9;
            int r = atomicAdd(&curl[b], 1);
            int pos = basel[b] + r;
            stage[pos] = ((unsigned)(ed[j] & (BKN2 - 1)) << 17) | (unsigned)es[j];
            bkt[pos] = (unsigned char)b;
        }
    }
    __syncthreads();
    for (int i = t; i < ne; i += 256) {
        int b = bkt[i];
        packed[(size_t)b * BCAP + gbase[b] + (i - basel[b])] = stage[i];
    }
}

// ---------------- pass C: per-bucket CSR finalize (inline bucket prefix) ------
__global__ __launch_bounds__(256) void csr_build2(
        const unsigned int* __restrict__ packed, const int* __restrict__ bcur,
        int* __restrict__ row_ptr, int* __restrict__ csr_src) {
    __shared__ int cnt[BKN2], scn[BKN2], cur[BKN2];
    int b = blockIdx.x, t = threadIdx.x;
    // ebase = sum_{b'<b} bcur[b'] via block reduce (scn[0..255] scratch)
    scn[t] = (t < b) ? bcur[t] : 0;
    __syncthreads();
    for (int off = 128; off >= 1; off >>= 1) {
        if (t < off) scn[t] += scn[t + off];
        __syncthreads();
    }
    int ebase_b = scn[0];
    __syncthreads();

    int nbase = b * BKN2;
    int nn = min(BKN2, N_NODES - nbase);
    int ec = bcur[b];
    size_t pbase = (size_t)b * BCAP;
    int cbase = ebase_b + nbase;
    cnt[t] = (t < nn) ? 1 : 0;
    cnt[t + 256] = (t + 256 < nn) ? 1 : 0;
    __syncthreads();
    for (int i = t; i < ec; i += 256)
        atomicAdd(&cnt[packed[pbase + i] >> 17], 1);
    __syncthreads();
    scn[t] = cnt[t];
    scn[t + 256] = cnt[t + 256];
    __syncthreads();
    for (int off = 1; off < BKN2; off <<= 1) {
        int u0 = (t >= off) ? scn[t - off] : 0;
        int u1 = (t + 256 >= off) ? scn[t + 256 - off] : 0;
        __syncthreads();
        scn[t] += u0;
        scn[t + 256] += u1;
        __syncthreads();
    }
    #pragma unroll
    for (int q = 0; q < 2; ++q) {
        int idx = t + q * 256;
        if (idx < nn) {
            int offi = scn[idx] - cnt[idx];
            row_ptr[nbase + idx] = cbase + offi;
            csr_src[cbase + offi] = nbase + idx;   // self-loop first
            cur[idx] = offi + 1;
        }
    }
    if (b == NB2 - 1 && t == 0) row_ptr[N_NODES] = cbase + ec + nn;
    __syncthreads();
    for (int i = t; i < ec; i += 256) {
        unsigned p = packed[pbase + i];
        int dl = p >> 17, s = (int)(p & 0x1FFFFu);
        int pos = atomicAdd(&cur[dl], 1);
        csr_src[cbase + pos] = s;
    }
}

// ---------------- MFMA input GEMM: h = leaky(x @ W_in + b), bf16 out ---------
// 64 rows/block; x tile + W^T staged as bf16 in LDS (fp32->bf16 inline).
// Per wave 16 rows x 64 cols via 16x mfma_f32_16x16x32_bf16.
#define SAW 136   // bf16 row stride for sA/sWT (pad 8)

__global__ __launch_bounds__(256) void gemm_in_mfma(
        const float* __restrict__ X, const float* __restrict__ W,
        const float* __restrict__ bias, unsigned* __restrict__ C) {
    __shared__ __align__(16) unsigned short sA[64][SAW];   // 17.4 KB
    __shared__ __align__(16) unsigned short sWT[64][SAW];  // 17.4 KB
    __shared__ float sB[64];
    int t = threadIdx.x;
    int r0 = blockIdx.x * 64;
    // stage X rows -> bf16 (coalesced float4)
    #pragma unroll
    for (int it = 0; it < 8; ++it) {
        int idx = it * 256 + t;          // 0..2047 float4s
        int r = idx >> 5, c4 = (idx & 31) * 4;
        int gr = r0 + r;
        float4 v = make_float4(0.f, 0.f, 0.f, 0.f);
        if (gr < N_NODES) v = *(const float4*)&X[(size_t)gr * F_IN + c4];
        unsigned* dst = (unsigned*)&sA[r][c4];
        dst[0] = cvt_pk_bf16(v.x, v.y);
        dst[1] = cvt_pk_bf16(v.z, v.w);
    }
    // stage W transposed -> bf16 : W[k][j] -> sWT[j][k]
    #pragma unroll
    for (int it = 0; it < 8; ++it) {
        int idx = it * 256 + t;          // 0..2047 float4s
        int k = idx >> 4, j4 = (idx & 15) * 4;
        float4 v = *(const float4*)&W[k * 64 + j4];
        sWT[j4 + 0][k] = f2bf(v.x);
        sWT[j4 + 1][k] = f2bf(v.y);
        sWT[j4 + 2][k] = f2bf(v.z);
        sWT[j4 + 3][k] = f2bf(v.w);
    }
    if (t < 64) sB[t] = bias[t];
    __syncthreads();

    int wave = t >> 6, lane = t & 63;
    int cj = lane & 15, kq = lane >> 4;
    int lrow = wave * 16 + cj;
    f32x4 zero = {0.f, 0.f, 0.f, 0.f};
    f32x4 acc[4] = {zero, zero, zero, zero};
    #pragma unroll
    for (int q = 0; q < 4; ++q) {
        short8 a = *(const short8*)&sA[lrow][q * 32 + kq * 8];
        #pragma unroll
        for (int ct = 0; ct < 4; ++ct) {
            short8 bfr = *(const short8*)&sWT[ct * 16 + cj][q * 32 + kq * 8];
            acc[ct] = __builtin_amdgcn_mfma_f32_16x16x32_bf16(a, bfr, acc[ct], 0, 0, 0);
        }
    }
    __syncthreads();   // sA reads done; reuse as f32 tile (stride 65)
    float* tl = (float*)&sA[0][0] + wave * (16 * 65);
    #pragma unroll
    for (int ct = 0; ct < 4; ++ct) {
        float bsv = sB[ct * 16 + cj];
        #pragma unroll
        for (int r = 0; r < 4; ++r) {
            float v = acc[ct][r] + bsv;
            v = v > 0.f ? v : 0.01f * v;
            tl[(kq * 4 + r) * 65 + ct * 16 + cj] = v;
        }
    }
    unsigned ur[8];
    int trow = lane >> 2, tcb = lane & 3;
    #pragma unroll
    for (int i = 0; i < 8; ++i) {
        float2 fp = *(const float2*)&tl[trow * 65 + tcb * 16 + i * 2];
        ur[i] = cvt_pk_bf16(fp.x, fp.y);
    }
    int grow = r0 + wave * 16 + trow;
    if (grow < N_NODES) {
        uint4* dst = (uint4*)&C[(size_t)grow * 32 + tcb * 8];
        dst[0] = make_uint4(ur[0], ur[1], ur[2], ur[3]);
        dst[1] = make_uint4(ur[4], ur[5], ur[6], ur[7]);
    }
}

// ---------------- MFMA layer GEMM (as R12, sTile stride 65) ----------------
__global__ __launch_bounds__(256) void gemm_mfma_kernel(
        const unsigned* __restrict__ A32, const float* __restrict__ W,
        const float* __restrict__ asrc, const float* __restrict__ adst,
        unsigned* __restrict__ C, float* __restrict__ as_, float* __restrict__ ad_) {
    __shared__ __align__(16) unsigned short sWT[64][72];  // 9 KB
    __shared__ float sAv[64], sDv[64];
    __shared__ __align__(16) float sTile[4][16 * 65];     // 16.6 KB
    int t = threadIdx.x;
    for (int i = t; i < 64 * 64; i += 256) {
        int k = i >> 6, j = i & 63;
        sWT[j][k] = f2bf(W[i]);
    }
    if (t < 64) { sAv[t] = asrc[t]; sDv[t] = adst[t]; }
    __syncthreads();

    int wave = t >> 6, lane = t & 63;
    int r0 = blockIdx.x * 64 + wave * 16;
    int cj = lane & 15, kq = lane >> 4;

    int ra = r0 + cj;
    if (ra >= N_NODES) ra = N_NODES - 1;
    const short8* arow = (const short8*)&A32[(size_t)ra * 32];
    short8 a0 = arow[kq];
    short8 a1 = arow[4 + kq];

    f32x4 zero = {0.f, 0.f, 0.f, 0.f};
    f32x4 acc[4] = {zero, zero, zero, zero};
    #pragma unroll
    for (int ct = 0; ct < 4; ++ct) {
        short8 b0 = *(const short8*)&sWT[16 * ct + cj][kq * 8];
        short8 b1 = *(const short8*)&sWT[16 * ct + cj][32 + kq * 8];
        acc[ct] = __builtin_amdgcn_mfma_f32_16x16x32_bf16(a0, b0, acc[ct], 0, 0, 0);
        acc[ct] = __builtin_amdgcn_mfma_f32_16x16x32_bf16(a1, b1, acc[ct], 0, 0, 0);
    }

    float av[4], dv[4];
    #pragma unroll
    for (int ct = 0; ct < 4; ++ct) { av[ct] = sAv[ct * 16 + cj]; dv[ct] = sDv[ct * 16 + cj]; }
    #pragma unroll
    for (int r = 0; r < 4; ++r) {
        float ds = acc[0][r] * av[0] + acc[1][r] * av[1] + acc[2][r] * av[2] + acc[3][r] * av[3];
        float dd = acc[0][r] * dv[0] + acc[1][r] * dv[1] + acc[2][r] * dv[2] + acc[3][r] * dv[3];
        #pragma unroll
        for (int off = 1; off < 16; off <<= 1) {
            ds += __shfl_xor(ds, off);
            dd += __shfl_xor(dd, off);
        }
        int grow = r0 + kq * 4 + r;
        if (cj == 0 && grow < N_NODES) { as_[grow] = ds; ad_[grow] = dd; }
    }

    float* tl = sTile[wave];
    #pragma unroll
    for (int ct = 0; ct < 4; ++ct)
        #pragma unroll
        for (int r = 0; r < 4; ++r)
            tl[(kq * 4 + r) * 65 + ct * 16 + cj] = acc[ct][r];
    unsigned ur[8];
    int trow = lane >> 2, tcb = lane & 3;
    #pragma unroll
    for (int i = 0; i < 8; ++i) {
        float2 fp = *(const float2*)&tl[trow * 65 + tcb * 16 + i * 2];
        ur[i] = cvt_pk_bf16(fp.x, fp.y);
    }
    int grow = r0 + trow;
    if (grow < N_NODES) {
        uint4* dst = (uint4*)&C[(size_t)grow * 32 + tcb * 8];
        dst[0] = make_uint4(ur[0], ur[1], ur[2], ur[3]);
        dst[1] = make_uint4(ur[4], ur[5], ur[6], ur[7]);
    }
}

// ---------------- fused aggregation: 16-lane groups, uint2 gathers ----------
// Phase 1: lane=edge staging (ex, src) + denom reduce.
// Phase 2: group g (lanes 16g..16g+15) processes edges g, g+4, ... ; each lane
// loads uint2 (4 bf16 features); cross-group reduce via shfl_xor 16/32.
__global__ __launch_bounds__(256) void agg_kernel(
        const int* __restrict__ row_ptr, const int* __restrict__ csr_src,
        const float* __restrict__ as_, const float* __restrict__ ad_,
        const unsigned* __restrict__ hw32, const float* __restrict__ bc,
        unsigned* __restrict__ hout32) {
    __shared__ float exbuf[4][MAXD];
    __shared__ int   sbuf[4][MAXD];
    int wave = threadIdx.x >> 6, lane = threadIdx.x & 63;
    int node = blockIdx.x * 4 + wave;
    if (node >= N_NODES) return;
    int rs = row_ptr[node], re = row_ptr[node + 1];
    int deg = re - rs;
    float aD = ad_[node];
    float psum = 0.f;
    for (int i = lane; i < deg; i += 64) {
        int s = csr_src[rs + i];
        float v = as_[s] + aD;
        v = v > 0.f ? v : 0.2f * v;
        float p = __expf(v);
        if (deg <= MAXD) { exbuf[wave][i] = p; sbuf[wave][i] = s; }
        psum += p;
    }
    #pragma unroll
    for (int off = 32; off >= 1; off >>= 1) psum += __shfl_xor(psum, off);
    float inv = 1.f / (psum + 1e-16f);

    int g = lane >> 4, fl16 = lane & 15;
    float a0 = 0.f, a1 = 0.f, a2 = 0.f, a3 = 0.f;
    if (deg <= MAXD) {
        int i = g;
        for (; i + 4 < deg; i += 8) {
            float w0 = exbuf[wave][i], w1 = exbuf[wave][i + 4];
            int s0 = sbuf[wave][i], s1 = sbuf[wave][i + 4];
            uint2 p0 = *(const uint2*)&hw32[((unsigned)s0 << 5) | (fl16 * 2)];
            uint2 p1 = *(const uint2*)&hw32[((unsigned)s1 << 5) | (fl16 * 2)];
            a0 += w0 * bf_lo(p0.x) + w1 * bf_lo(p1.x);
            a1 += w0 * bf_hi(p0.x) + w1 * bf_hi(p1.x);
            a2 += w0 * bf_lo(p0.y) + w1 * bf_lo(p1.y);
            a3 += w0 * bf_hi(p0.y) + w1 * bf_hi(p1.y);
        }
        for (; i < deg; i += 4) {
            float w = exbuf[wave][i];
            int s = sbuf[wave][i];
            uint2 p = *(const uint2*)&hw32[((unsigned)s << 5) | (fl16 * 2)];
            a0 += w * bf_lo(p.x);
            a1 += w * bf_hi(p.x);
            a2 += w * bf_lo(p.y);
            a3 += w * bf_hi(p.y);
        }
    } else {
        for (int i = g; i < deg; i += 4) {
            int s = csr_src[rs + i];
            float v = as_[s] + aD;
            v = v > 0.f ? v : 0.2f * v;
            float w = __expf(v);
            uint2 p = *(const uint2*)&hw32[((unsigned)s << 5) | (fl16 * 2)];
            a0 += w * bf_lo(p.x);
            a1 += w * bf_hi(p.x);
            a2 += w * bf_lo(p.y);
            a3 += w * bf_hi(p.y);
        }
    }
    a0 += __shfl_xor(a0, 16); a0 += __shfl_xor(a0, 32);
    a1 += __shfl_xor(a1, 16); a1 += __shfl_xor(a1, 32);
    a2 += __shfl_xor(a2, 16); a2 += __shfl_xor(a2, 32);
    a3 += __shfl_xor(a3, 16); a3 += __shfl_xor(a3, 32);
    if (g == 0) {
        float4 bv = *(const float4*)&bc[fl16 * 4];
        float v0 = a0 * inv + bv.x; v0 = v0 > 0.f ? v0 : 0.01f * v0;
        float v1 = a1 * inv + bv.y; v1 = v1 > 0.f ? v1 : 0.01f * v1;
        float v2 = a2 * inv + bv.z; v2 = v2 > 0.f ? v2 : 0.01f * v2;
        float v3 = a3 * inv + bv.w; v3 = v3 > 0.f ? v3 : 0.01f * v3;
        *(uint2*)&hout32[((unsigned)node << 5) | (fl16 * 2)] =
            make_uint2(cvt_pk_bf16(v0, v1), cvt_pk_bf16(v2, v3));
    }
}

// ---------------- output GEMM + log_softmax (bf16 h input) ----------------
__global__ __launch_bounds__(256) void out_logsoftmax_kernel(
        const unsigned* __restrict__ h32, const float* __restrict__ W,
        const float* __restrict__ b, float* __restrict__ out) {
    __shared__ float sW[H_DIM * C_OUT];
    __shared__ float sh[16][H_DIM];
    __shared__ float sb[C_OUT];
    int t = threadIdx.x;
    for (int i = t; i < H_DIM * C_OUT; i += 256) sW[i] = W[i];
    if (t < C_OUT) sb[t] = b[t];
    int row0 = blockIdx.x * 16;
    #pragma unroll
    for (int it = 0; it < 2; ++it) {
        int idx = it * 256 + t;
        int r = idx >> 5, c2 = idx & 31;
        unsigned u = h32[((unsigned)(row0 + r) << 5) | c2];
        sh[r][c2 * 2] = bf_lo(u);
        sh[r][c2 * 2 + 1] = bf_hi(u);
    }
    __syncthreads();
    int r = t >> 4, c = t & 15;
    float acc = sb[c];
    #pragma unroll
    for (int k = 0; k < H_DIM; ++k) acc += sh[r][k] * sW[k * C_OUT + c];
    float m = acc;
    #pragma unroll
    for (int off = 8; off >= 1; off >>= 1) m = fmaxf(m, __shfl_xor(m, off, 16));
    float e = __expf(acc - m);
    float ssum = e;
    #pragma unroll
    for (int off = 8; off >= 1; off >>= 1) ssum += __shfl_xor(ssum, off, 16);
    out[(row0 + r) * C_OUT + c] = acc - m - __logf(ssum);
}

extern "C" void kernel_launch(void* const* d_in, const int* in_sizes, int n_in,
                              void* d_out, int out_size, void* d_ws, size_t ws_size,
                              hipStream_t stream) {
    const float* x     = (const float*)d_in[0];
    const void*  eidx  = d_in[1];
    const float* W_in  = (const float*)d_in[3];
    const float* b_in  = (const float*)d_in[4];
    const float* Wc    = (const float*)d_in[5];
    const float* a_src = (const float*)d_in[6];
    const float* a_dst = (const float*)d_in[7];
    const float* bc    = (const float*)d_in[8];
    const float* W_out = (const float*)d_in[9];
    const float* b_out = (const float*)d_in[10];
    float* out = (float*)d_out;

    // workspace layout: h, hw packed-bf16 node tables (N x 32 uints)
    unsigned* h     = (unsigned*)d_ws;                     // N*32 uints
    unsigned* hw    = h + (size_t)N_NODES * 32;            // N*32 uints
    float* as_      = (float*)(hw + (size_t)N_NODES * 32); // N
    float* ad_      = as_ + N_NODES;                       // N
    int*   row_ptr  = (int*)(ad_ + N_NODES);               // N+1
    int*   csr_src  = row_ptr + N_NODES + 1;               // E+N
    unsigned int* packed = (unsigned int*)(csr_src + NTOT);// NB2*BCAP
    int*   bcur     = (int*)(packed + (size_t)NB2 * BCAP); // NB2

    hipMemsetAsync(bcur, 0, NB2 * sizeof(int), stream);
    bucket_scatter2<<<PB, 256, 0, stream>>>(eidx, bcur, packed);
    csr_build2<<<NB2, 256, 0, stream>>>(packed, bcur, row_ptr, csr_src);

    gemm_in_mfma<<<(N_NODES + 63) / 64, 256, 0, stream>>>(x, W_in, b_in, h);

    unsigned* hin = h;
    unsigned* hx  = hw;
    int mblocks = (N_NODES + 63) / 64;
    for (int l = 0; l < L_LAYERS; ++l) {
        gemm_mfma_kernel<<<mblocks, 256, 0, stream>>>(
            hin, Wc + l * H_DIM * H_DIM,
            a_src + l * H_DIM, a_dst + l * H_DIM, hx, as_, ad_);
        agg_kernel<<<(N_NODES + 3) / 4, 256, 0, stream>>>(
            row_ptr, csr_src, as_, ad_, hx, bc + l * H_DIM, hin);
    }

    out_logsoftmax_kernel<<<N_NODES / 16, 256, 0, stream>>>(hin, W_out, b_out, out);
}